// Round 1
// baseline (127.078 us; speedup 1.0000x reference)
//
#include <hip/hip_runtime.h>

constexpr int B = 2, C = 32, H = 96, W = 128, D = 48, NSRC = 2;
constexpr int NV = NSRC + 1;
constexpr int HWsz = H * W;

// ---------------------------------------------------------------------------
// Setup: per (view, b) compute rot(3x3) + trans(3) of  src_p @ inv(ref_p)
// where both are combined projections (K @ ext[:3,:4], last row [0,0,0,1]).
// Affine inverse: M=[[A,t],[0,1]] -> [[A^-1, -A^-1 t],[0,1]].
// ---------------------------------------------------------------------------
__global__ void setup_proj(const float* __restrict__ ref_proj,
                           const float* __restrict__ src_projs,
                           float* __restrict__ ws) {
  int t = threadIdx.x;
  if (t >= NSRC * B) return;
  int v = t / B, b = t % B;
  const float* rp = ref_proj + b * 32;             // (2,4,4)
  const float* sp = src_projs + (v * B + b) * 32;  // (nsrc,B,2,4,4)

  double Kr[3][3], Er[3][4], Ks[3][3], Es[3][4];
  for (int r = 0; r < 3; r++)
    for (int c = 0; c < 3; c++) { Kr[r][c] = rp[16 + r * 4 + c]; Ks[r][c] = sp[16 + r * 4 + c]; }
  for (int r = 0; r < 3; r++)
    for (int c = 0; c < 4; c++) { Er[r][c] = rp[r * 4 + c]; Es[r][c] = sp[r * 4 + c]; }

  double Ar[3][3], tr[3], As[3][3], ts[3];
  for (int r = 0; r < 3; r++) {
    for (int c = 0; c < 3; c++) {
      double a = 0, s = 0;
      for (int k = 0; k < 3; k++) { a += Kr[r][k] * Er[k][c]; s += Ks[r][k] * Es[k][c]; }
      Ar[r][c] = a; As[r][c] = s;
    }
    double a = 0, s = 0;
    for (int k = 0; k < 3; k++) { a += Kr[r][k] * Er[k][3]; s += Ks[r][k] * Es[k][3]; }
    tr[r] = a; ts[r] = s;
  }

  double det = Ar[0][0] * (Ar[1][1] * Ar[2][2] - Ar[1][2] * Ar[2][1])
             - Ar[0][1] * (Ar[1][0] * Ar[2][2] - Ar[1][2] * Ar[2][0])
             + Ar[0][2] * (Ar[1][0] * Ar[2][1] - Ar[1][1] * Ar[2][0]);
  double inv[3][3];
  inv[0][0] =  (Ar[1][1] * Ar[2][2] - Ar[1][2] * Ar[2][1]) / det;
  inv[0][1] = -(Ar[0][1] * Ar[2][2] - Ar[0][2] * Ar[2][1]) / det;
  inv[0][2] =  (Ar[0][1] * Ar[1][2] - Ar[0][2] * Ar[1][1]) / det;
  inv[1][0] = -(Ar[1][0] * Ar[2][2] - Ar[1][2] * Ar[2][0]) / det;
  inv[1][1] =  (Ar[0][0] * Ar[2][2] - Ar[0][2] * Ar[2][0]) / det;
  inv[1][2] = -(Ar[0][0] * Ar[1][2] - Ar[0][2] * Ar[1][0]) / det;
  inv[2][0] =  (Ar[1][0] * Ar[2][1] - Ar[1][1] * Ar[2][0]) / det;
  inv[2][1] = -(Ar[0][0] * Ar[2][1] - Ar[0][1] * Ar[2][0]) / det;
  inv[2][2] =  (Ar[0][0] * Ar[1][1] - Ar[0][1] * Ar[1][0]) / det;

  double rot[3][3], trans[3];
  for (int r = 0; r < 3; r++)
    for (int c = 0; c < 3; c++) {
      double a = 0;
      for (int k = 0; k < 3; k++) a += As[r][k] * inv[k][c];
      rot[r][c] = a;
    }
  for (int r = 0; r < 3; r++) {
    double a = 0;
    for (int k = 0; k < 3; k++) a += rot[r][k] * tr[k];
    trans[r] = ts[r] - a;
  }

  float* o = ws + t * 12;
  for (int r = 0; r < 3; r++)
    for (int c = 0; c < 3; c++) o[r * 3 + c] = (float)rot[r][c];
  for (int r = 0; r < 3; r++) o[9 + r] = (float)trans[r];
}

// ---------------------------------------------------------------------------
// Kernel 1: cost[b,d,h,w] = sum_c variance * w_reg[c] + b_reg
// One thread per (b,d,h,w). Bilinear setup once per view; channel loop.
// ---------------------------------------------------------------------------
__global__ __launch_bounds__(256) void cost_kernel(
    const float* __restrict__ ref, const float* __restrict__ src,
    const float* __restrict__ dvals, const float* __restrict__ wreg,
    const float* __restrict__ breg, const float* __restrict__ pr,
    float* __restrict__ cost_out) {
  int idx = blockIdx.x * 256 + threadIdx.x;
  if (idx >= B * D * H * W) return;
  int w = idx % W;
  int h = (idx / W) % H;
  int d = (idx / (W * H)) % D;
  int b = idx / (W * H * D);
  float depth = dvals[b * D + d];
  float fx = (float)w, fy = (float)h;

  int   off[NSRC][4];
  float wgt[NSRC][4];
#pragma unroll
  for (int v = 0; v < NSRC; v++) {
    const float* p = pr + (v * B + b) * 12;
    float X = (p[0] * fx + p[1] * fy + p[2]) * depth + p[9];
    float Y = (p[3] * fx + p[4] * fy + p[5]) * depth + p[10];
    float Z = (p[6] * fx + p[7] * fy + p[8]) * depth + p[11];
    float px = X / Z, py = Y / Z;
    float x0f = floorf(px), y0f = floorf(py);
    float wx = px - x0f, wy = py - y0f;
    int x0 = (int)x0f, y0 = (int)y0f;
    int x1 = x0 + 1, y1 = y0 + 1;
    float vx0 = (x0 >= 0 && x0 < W) ? 1.f : 0.f;
    float vx1 = (x1 >= 0 && x1 < W) ? 1.f : 0.f;
    float vy0 = (y0 >= 0 && y0 < H) ? 1.f : 0.f;
    float vy1 = (y1 >= 0 && y1 < H) ? 1.f : 0.f;
    int cx0 = min(max(x0, 0), W - 1), cx1 = min(max(x1, 0), W - 1);
    int cy0 = min(max(y0, 0), H - 1), cy1 = min(max(y1, 0), H - 1);
    int base = (v * B + b) * C * HWsz;
    off[v][0] = base + cy0 * W + cx0;
    off[v][1] = base + cy0 * W + cx1;
    off[v][2] = base + cy1 * W + cx0;
    off[v][3] = base + cy1 * W + cx1;
    wgt[v][0] = (1.f - wx) * (1.f - wy) * vx0 * vy0;
    wgt[v][1] = wx * (1.f - wy) * vx1 * vy0;
    wgt[v][2] = (1.f - wx) * wy * vx0 * vy1;
    wgt[v][3] = wx * wy * vx1 * vy1;
  }

  int refoff = b * C * HWsz + h * W + w;
  const float inv_nv = 1.f / (float)NV;
  float cost = 0.f;
#pragma unroll 4
  for (int c = 0; c < C; c++) {
    float rv = ref[refoff + c * HWsz];
    float s = rv, sq = rv * rv;
#pragma unroll
    for (int v = 0; v < NSRC; v++) {
      int co = c * HWsz;
      float smp = wgt[v][0] * src[off[v][0] + co]
                + wgt[v][1] * src[off[v][1] + co]
                + wgt[v][2] * src[off[v][2] + co]
                + wgt[v][3] * src[off[v][3] + co];
      s += smp;
      sq += smp * smp;
    }
    float m = s * inv_nv;
    float var = sq * inv_nv - m * m;
    cost += var * wreg[c];
  }
  cost += breg[0];
  cost_out[idx] = cost;  // idx == ((b*D+d)*H+h)*W+w == prob layout
}

// ---------------------------------------------------------------------------
// Kernel 2: per (b,h,w) column: softmax over D (in place in prob region),
// expected depth, photometric confidence.
// ---------------------------------------------------------------------------
__global__ __launch_bounds__(256) void softmax_kernel(
    const float* __restrict__ dvals, float* __restrict__ out) {
  int idx = blockIdx.x * 256 + threadIdx.x;
  if (idx >= B * HWsz) return;
  int b = idx / HWsz;
  int hw = idx % HWsz;
  float* prob = out + 2 * B * HWsz;

  float p[D];
  float mx = -1e30f;
#pragma unroll
  for (int d = 0; d < D; d++) {
    p[d] = prob[(b * D + d) * HWsz + hw];
    mx = fmaxf(mx, p[d]);
  }
  float sum = 0.f;
#pragma unroll
  for (int d = 0; d < D; d++) {
    p[d] = expf(p[d] - mx);
    sum += p[d];
  }
  float inv = 1.f / sum;
  float depth = 0.f, didxf = 0.f;
#pragma unroll
  for (int d = 0; d < D; d++) {
    p[d] *= inv;
    depth += p[d] * dvals[b * D + d];
    didxf += p[d] * (float)d;
    prob[(b * D + d) * HWsz + hw] = p[d];
  }
  int di = (int)didxf;
  di = min(max(di, 0), D - 1);
  float conf = 0.f;
#pragma unroll
  for (int d = 0; d < D; d++) {
    conf += ((d == di) || (d == di + 1)) ? p[d] : 0.f;
  }
  out[idx] = depth;
  out[B * HWsz + idx] = conf;
}

extern "C" void kernel_launch(void* const* d_in, const int* in_sizes, int n_in,
                              void* d_out, int out_size, void* d_ws, size_t ws_size,
                              hipStream_t stream) {
  const float* ref_feature  = (const float*)d_in[0];
  const float* src_features = (const float*)d_in[1];
  const float* ref_proj     = (const float*)d_in[2];
  const float* src_projs    = (const float*)d_in[3];
  const float* depth_values = (const float*)d_in[4];
  const float* w_reg        = (const float*)d_in[5];
  const float* b_reg        = (const float*)d_in[6];

  float* out = (float*)d_out;
  float* ws  = (float*)d_ws;
  float* cost = out + 2 * B * HWsz;  // prob_volume region doubles as cost scratch

  setup_proj<<<1, 64, 0, stream>>>(ref_proj, src_projs, ws);

  int n1 = B * D * H * W;
  cost_kernel<<<(n1 + 255) / 256, 256, 0, stream>>>(
      ref_feature, src_features, depth_values, w_reg, b_reg, ws, cost);

  int n2 = B * HWsz;
  softmax_kernel<<<(n2 + 255) / 256, 256, 0, stream>>>(depth_values, out);
}